// Round 1
// baseline (76.611 us; speedup 1.0000x reference)
//
#include <hip/hip_runtime.h>
#include <math.h>

// Problem constants (from setup_inputs): B=4, C=4, H=96, W=96
#define BB 4
#define CC 4
#define HH 96
#define WW 96
#define NN (HH * WW)
#define BIGF 1e10f

// ---------------------------------------------------------------------------
// Kernel 1: pred = argmax over channel axis of output [B,C,H,W] -> [B,N] u8
// ---------------------------------------------------------------------------
__global__ void k_pred(const float* __restrict__ out, unsigned char* __restrict__ pred) {
    int idx = blockIdx.x * blockDim.x + threadIdx.x;
    if (idx >= BB * NN) return;
    int b = idx / NN;
    int p = idx - b * NN;
    const float* base = out + (size_t)b * CC * NN + p;
    float best = base[0];
    int bc = 0;
    #pragma unroll
    for (int c = 1; c < CC; ++c) {
        float v = base[(size_t)c * NN];
        if (v > best) { best = v; bc = c; }   // strict > keeps first-max (argmax semantics)
    }
    pred[idx] = (unsigned char)bc;
}

// ---------------------------------------------------------------------------
// Kernel 2: boundary masks for pred and target.
// boundary[i,j] = any in-bounds 4-neighbor has a different label.
// ---------------------------------------------------------------------------
__global__ void k_masks(const unsigned char* __restrict__ pred,
                        const int* __restrict__ tgt,
                        unsigned char* __restrict__ mP,
                        unsigned char* __restrict__ mT) {
    int idx = blockIdx.x * blockDim.x + threadIdx.x;
    if (idx >= BB * NN) return;
    int b = idx / NN;
    int p = idx - b * NN;
    int i = p / WW;
    int j = p - i * WW;

    {
        int v = pred[idx];
        bool bd = false;
        if (i > 0)      bd |= (pred[idx - WW] != v);
        if (i < HH - 1) bd |= (pred[idx + WW] != v);
        if (j > 0)      bd |= (pred[idx - 1]  != v);
        if (j < WW - 1) bd |= (pred[idx + 1]  != v);
        mP[idx] = bd ? 1 : 0;
    }
    {
        int v = tgt[idx];
        bool bd = false;
        if (i > 0)      bd |= (tgt[idx - WW] != v);
        if (i < HH - 1) bd |= (tgt[idx + WW] != v);
        if (j > 0)      bd |= (tgt[idx - 1]  != v);
        if (j < WW - 1) bd |= (tgt[idx + 1]  != v);
        mT[idx] = bd ? 1 : 0;
    }
}

// ---------------------------------------------------------------------------
// Kernel 3: column pass of exact squared EDT.
// For mask m (m = b*2 + e, e=0 -> maskP, e=1 -> maskT):
//   g[m][i][j] = min over qi with mask[b][qi][j] of (i-qi)^2, else BIG.
// One thread per (m, i, j).
// ---------------------------------------------------------------------------
__global__ void k_col(const unsigned char* __restrict__ mP,
                      const unsigned char* __restrict__ mT,
                      float* __restrict__ g) {
    int idx = blockIdx.x * blockDim.x + threadIdx.x;
    if (idx >= 8 * NN) return;
    int m = idx / NN;
    int p = idx - m * NN;
    int b = m >> 1;
    int e = m & 1;
    int i = p / WW;
    int j = p - i * WW;
    const unsigned char* mask = (e ? mT : mP) + b * NN;
    float best = BIGF;
    for (int qi = 0; qi < HH; ++qi) {
        if (mask[qi * WW + j]) {
            float d = (float)(i - qi) * (float)(i - qi);
            best = fminf(best, d);
        }
    }
    g[idx] = best;
}

// ---------------------------------------------------------------------------
// Kernel 4: row pass of EDT fused with masked row-max.
//   D[i][j] = min over j' of (g[i][j'] + (j-j')^2)   (exact sq. EDT of mask e)
//   rowmax[m][i] = max over j where otherMask[b][i][j] of D[i][j], else -BIG
// where otherMask = maskP if e==1 (fwd: max over pred pts of dist-to-tgt),
//                   maskT if e==0 (bwd).
// One block per (m, i); 128 threads (96 active for the row).
// ---------------------------------------------------------------------------
__global__ void k_row(const float* __restrict__ g,
                      const unsigned char* __restrict__ mP,
                      const unsigned char* __restrict__ mT,
                      float* __restrict__ rowmax) {
    int blk = blockIdx.x;          // m*HH + i
    int m = blk / HH;
    int i = blk - m * HH;
    int b = m >> 1;
    int e = m & 1;
    int t = threadIdx.x;

    __shared__ float sh_g[WW];
    __shared__ float red[128];

    if (t < WW) sh_g[t] = g[m * NN + i * WW + t];
    __syncthreads();

    float cand = -BIGF;
    if (t < WW) {
        int j = t;
        float best = BIGF;
        #pragma unroll 8
        for (int jp = 0; jp < WW; ++jp) {
            float dj = (float)(j - jp);
            best = fminf(best, sh_g[jp] + dj * dj);
        }
        const unsigned char* om = (e ? mP : mT) + b * NN;
        if (om[i * WW + j]) cand = best;
    }
    red[t] = cand;
    __syncthreads();
    for (int s = 64; s > 0; s >>= 1) {
        if (t < s) red[t] = fmaxf(red[t], red[t + s]);
        __syncthreads();
    }
    if (t == 0) rowmax[blk] = red[0];
}

// ---------------------------------------------------------------------------
// Kernel 5: final reduction. 8 waves, wave m reduces rowmax[m][*] (96 vals),
// then thread 0 combines: per batch h = sqrt(max(fwd,bwd,0)); out = mean.
// ---------------------------------------------------------------------------
__global__ void k_final(const float* __restrict__ rowmax, float* __restrict__ outv) {
    __shared__ float smax[8];
    int t = threadIdx.x;
    int m = t >> 6;      // wave id = mask id
    int l = t & 63;
    float v = -BIGF;
    for (int i = l; i < HH; i += 64) v = fmaxf(v, rowmax[m * HH + i]);
    #pragma unroll
    for (int off = 32; off > 0; off >>= 1) v = fmaxf(v, __shfl_down(v, off));
    if (l == 0) smax[m] = v;
    __syncthreads();
    if (t == 0) {
        float sum = 0.0f;
        #pragma unroll
        for (int b = 0; b < BB; ++b) {
            float bwd = smax[b * 2 + 0];   // EDT of maskP maxed over maskT pts
            float fwd = smax[b * 2 + 1];   // EDT of maskT maxed over maskP pts
            float h = sqrtf(fmaxf(fmaxf(fwd, bwd), 0.0f));
            sum += h;
        }
        outv[0] = sum / (float)BB;
    }
}

// ---------------------------------------------------------------------------
extern "C" void kernel_launch(void* const* d_in, const int* in_sizes, int n_in,
                              void* d_out, int out_size, void* d_ws, size_t ws_size,
                              hipStream_t stream) {
    const float* output = (const float*)d_in[0];   // [B,C,H,W] fp32
    const int* target   = (const int*)d_in[1];     // [B,H,W] int32
    float* outv         = (float*)d_out;           // scalar fp32

    // workspace layout
    unsigned char* ws8 = (unsigned char*)d_ws;
    unsigned char* pred  = ws8;                      // B*N u8     = 36864
    unsigned char* maskP = ws8 + BB * NN;            // B*N u8
    unsigned char* maskT = ws8 + 2 * BB * NN;        // B*N u8
    float* g       = (float*)(ws8 + 3 * BB * NN);    // 8*N f32    (3*BB*NN = 110592, 4-aligned)
    float* rowmax  = g + 8 * NN;                     // 8*H f32

    int threads = 256;
    k_pred <<<(BB * NN + threads - 1) / threads, threads, 0, stream>>>(output, pred);
    k_masks<<<(BB * NN + threads - 1) / threads, threads, 0, stream>>>(pred, target, maskP, maskT);
    k_col  <<<(8 * NN + threads - 1) / threads, threads, 0, stream>>>(maskP, maskT, g);
    k_row  <<<8 * HH, 128, 0, stream>>>(g, maskP, maskT, rowmax);
    k_final<<<1, 512, 0, stream>>>(rowmax, outv);
}